// Round 5
// baseline (11308.492 us; speedup 1.0000x reference)
//
#include <hip/hip_runtime.h>
#include <hip/hip_bf16.h>
#include <stdint.h>

// Problem constants
#define S_INPUT  1024
#define S_HIDDEN 2048
#define S_SEQ    256
#define S_BATCH  256
#define NWG_P    192    // persistent grid: 128 A-task + 64 B-task WGs

typedef __attribute__((ext_vector_type(8))) short bf16x8;   // 8 bf16 = 4 VGPRs
typedef __attribute__((ext_vector_type(4))) float f32x4;    // MFMA accumulator

__device__ __forceinline__ short f2bf(float f){
  union { float f; unsigned u; } v; v.f = f;
  unsigned r = v.u + 0x7fffu + ((v.u >> 16) & 1u);   // round-nearest-even
  return (short)(r >> 16);
}

// tanh via one v_exp_f32 + v_rcp_f32; exact at saturation.
__device__ __forceinline__ float tanh_fast(float x){
  float e = __expf(2.0f * x);
  return 1.0f - 2.0f / (e + 1.0f);
}

// Coherent (system-scope, L2-bypassing) 16B h-fragment load as 2x8B atomics.
__device__ __forceinline__ bf16x8 ld16_sys(const uint64_t* p){
  union { uint64_t w[2]; bf16x8 v; } u;
  u.w[0] = __hip_atomic_load((uint64_t*)p,     __ATOMIC_RELAXED, __HIP_MEMORY_SCOPE_SYSTEM);
  u.w[1] = __hip_atomic_load((uint64_t*)p + 1, __ATOMIC_RELAXED, __HIP_MEMORY_SCOPE_SYSTEM);
  return u.v;
}

// ---------------------------------------------------------------------------
// Flag-array grid barrier (no shared-counter RMW, no acquire/buffer_inv).
// bar[0] = generation; bar[(1+wg)*16] = per-WG arrival flag (64B spacing).
// Writers publish with RELEASE (system) -> h stores reach coherence point
// before flag visible. Readers use system-scope loads for h, so no L2
// invalidation is ever needed -> weights stay L2-resident across steps.
// ---------------------------------------------------------------------------
__device__ __forceinline__ void step_barrier(unsigned* bar, int ep, int bid)
{
  asm volatile("s_waitcnt vmcnt(0) lgkmcnt(0)" ::: "memory");
  __syncthreads();
  const int tid = threadIdx.x;
  if (bid == 0){
    for (;;){
      int ok = 1;
      if (tid >= 1 && tid < NWG_P){
        unsigned v = __hip_atomic_load(bar + (size_t)(1 + tid)*16,
                                       __ATOMIC_RELAXED, __HIP_MEMORY_SCOPE_SYSTEM);
        ok = (v >= (unsigned)ep);
      }
      if (__syncthreads_and(ok)) break;
      __builtin_amdgcn_s_sleep(1);
    }
    if (tid == 0)
      __hip_atomic_store(bar, (unsigned)ep, __ATOMIC_RELEASE, __HIP_MEMORY_SCOPE_SYSTEM);
  } else {
    if (tid == 0)
      __hip_atomic_store(bar + (size_t)(1 + bid)*16, (unsigned)ep,
                         __ATOMIC_RELEASE, __HIP_MEMORY_SCOPE_SYSTEM);
  }
  if (tid == 0){
    while (__hip_atomic_load(bar, __ATOMIC_RELAXED, __HIP_MEMORY_SCOPE_SYSTEM) < (unsigned)ep)
      __builtin_amdgcn_s_sleep(2);
  }
  __syncthreads();
}

// ---------------------------------------------------------------------------
// 64x64 GEMM core (both operands via LDS, cached loads) — used only for the
// prologue k_wcomb and step 0 (reads Acat/Wcat: no staleness possible).
// ---------------------------------------------------------------------------
__device__ __forceinline__ void gemm_core(const short* __restrict__ A, int lda,
                                          const short* __restrict__ B, int ldb,
                                          int bm, int bn, int ktiles,
                                          f32x4 acc[2][2], char* As, char* Bs)
{
  const int tid  = threadIdx.x;
  const int lane = tid & 63;
  const int wid  = tid >> 6;
  const int wm   = (wid >> 1) & 1;
  const int wn   = wid & 1;
  const int r15  = lane & 15;
  const int hi   = lane >> 4;
  const int ra0 = wm*32 + r15,  ra1 = ra0 + 16;
  const int rb0 = wn*32 + r15,  rb1 = rb0 + 16;

  const int c0 = tid, c1 = tid + 256;
  const int r0 = c0 >> 3, r1 = c1 >> 3;
  const int e0 = ((((c0 & 7) << 4) ^ ((r0 & 7) << 4)) >> 1);
  const int e1 = ((((c1 & 7) << 4) ^ ((r1 & 7) << 4)) >> 1);
  const short* pa0 = A + (size_t)(bm + r0)*lda + e0;
  const short* pa1 = A + (size_t)(bm + r1)*lda + e1;
  const short* pb0 = B + (size_t)(bn + r0)*ldb + e0;
  const short* pb1 = B + (size_t)(bn + r1)*ldb + e1;
  char* la0 = As + c0*16;  char* la1 = As + c1*16;
  char* lb0 = Bs + c0*16;  char* lb1 = Bs + c1*16;

  #define STAGE4(kt, s) do { \
    const int _ko = (kt)*64; const int _so = (s)*8192; \
    __builtin_amdgcn_global_load_lds((const __attribute__((address_space(1))) void*)(pa0 + _ko), \
                                     (__attribute__((address_space(3))) void*)(la0 + _so), 16, 0, 0); \
    __builtin_amdgcn_global_load_lds((const __attribute__((address_space(1))) void*)(pb0 + _ko), \
                                     (__attribute__((address_space(3))) void*)(lb0 + _so), 16, 0, 0); \
    __builtin_amdgcn_global_load_lds((const __attribute__((address_space(1))) void*)(pa1 + _ko), \
                                     (__attribute__((address_space(3))) void*)(la1 + _so), 16, 0, 0); \
    __builtin_amdgcn_global_load_lds((const __attribute__((address_space(1))) void*)(pb1 + _ko), \
                                     (__attribute__((address_space(3))) void*)(lb1 + _so), 16, 0, 0); \
  } while (0)

  STAGE4(0, 0);
  if (ktiles > 1) STAGE4(1, 1);
  if (ktiles > 2) STAGE4(2, 2);

  for (int t = 0; t < ktiles; ++t){
    const int rem = ktiles - 1 - t;
    if (rem >= 2)      asm volatile("s_waitcnt vmcnt(8)" ::: "memory");
    else if (rem == 1) asm volatile("s_waitcnt vmcnt(4)" ::: "memory");
    else               asm volatile("s_waitcnt vmcnt(0)" ::: "memory");
    asm volatile("s_barrier" ::: "memory");
    if (t + 3 < ktiles) STAGE4(t + 3, (t + 3) & 3);
    const char* as = As + (t & 3)*8192;
    const char* bs = Bs + (t & 3)*8192;
    #pragma unroll
    for (int kk = 0; kk < 2; ++kk){
      const int kb = kk*64 + hi*16;
      bf16x8 a0 = *(const bf16x8*)(as + ra0*128 + (kb ^ ((ra0 & 7) << 4)));
      bf16x8 a1 = *(const bf16x8*)(as + ra1*128 + (kb ^ ((ra1 & 7) << 4)));
      bf16x8 b0 = *(const bf16x8*)(bs + rb0*128 + (kb ^ ((rb0 & 7) << 4)));
      bf16x8 b1 = *(const bf16x8*)(bs + rb1*128 + (kb ^ ((rb1 & 7) << 4)));
      acc[0][0] = __builtin_amdgcn_mfma_f32_16x16x32_bf16(a0, b0, acc[0][0], 0, 0, 0);
      acc[0][1] = __builtin_amdgcn_mfma_f32_16x16x32_bf16(a0, b1, acc[0][1], 0, 0, 0);
      acc[1][0] = __builtin_amdgcn_mfma_f32_16x16x32_bf16(a1, b0, acc[1][0], 0, 0, 0);
      acc[1][1] = __builtin_amdgcn_mfma_f32_16x16x32_bf16(a1, b1, acc[1][1], 0, 0, 0);
    }
  }
  #undef STAGE4
}

// ---------------------------------------------------------------------------
// Step GEMM: A (=h) fragments loaded DIRECTLY to registers via system-scope
// coherent loads (no LDS, no staleness); B (=weights) via LDS pipeline with
// cached global_load_lds (L2 stays warm: no invalidations in this kernel).
// Ring-4 register slots, prefetch distance 3, 10 VMEM/iter per wave
// (2 B-lds + 8 h); counted vmcnt(20/10/0).
// h row stride: 2048 bf16 = 4096 B = 512 uint64  (R3 bug: had 256).
// ---------------------------------------------------------------------------
__device__ __forceinline__ void gemm_h(const short* __restrict__ h,
                                       const short* __restrict__ W,
                                       int bm, int bn,
                                       f32x4 acc[2][2], char* Bs)
{
  const int tid  = threadIdx.x;
  const int lane = tid & 63;
  const int wid  = tid >> 6;
  const int wm   = (wid >> 1) & 1;
  const int wn   = wid & 1;
  const int r15  = lane & 15;
  const int hi   = lane >> 4;
  const int rb0 = wn*32 + r15, rb1 = rb0 + 16;

  // B staging: 8KB tile = 512 x 16B chunks, 2 per thread
  const int c0 = tid, c1 = tid + 256;
  const int r0 = c0 >> 3, r1 = c1 >> 3;
  const int e0 = ((((c0 & 7) << 4) ^ ((r0 & 7) << 4)) >> 1);
  const int e1 = ((((c1 & 7) << 4) ^ ((r1 & 7) << 4)) >> 1);
  const short* pb0 = W + (size_t)(bn + r0)*S_HIDDEN + e0;
  const short* pb1 = W + (size_t)(bn + r1)*S_HIDDEN + e1;
  char* lb0 = Bs + c0*16;
  char* lb1 = Bs + c1*16;

  // h fragment addressing: row-major h [256][2048] bf16 = 512 uint64/row.
  // MFMA A-frag: lane holds row (lane&15), k = (lane>>4)*8 + j.
  const uint64_t* hq = (const uint64_t*)h;
  const int row0 = bm + wm*32 + r15;
  const int row1 = row0 + 16;
  const int q00 = row0*512 + hi*2;
  const int q10 = row1*512 + hi*2;

  bf16x8 h00[4], h01[4], h10[4], h11[4];   // [slot] — all indices compile-time

  #define STAGEB(u, s) do{ \
    const int _ko = (u)*64; const int _so = (s)*8192; \
    __builtin_amdgcn_global_load_lds((const __attribute__((address_space(1))) void*)(pb0 + _ko), \
        (__attribute__((address_space(3))) void*)(lb0 + _so), 16, 0, 0); \
    __builtin_amdgcn_global_load_lds((const __attribute__((address_space(1))) void*)(pb1 + _ko), \
        (__attribute__((address_space(3))) void*)(lb1 + _so), 16, 0, 0); \
  }while(0)
  #define LOADH(u, s) do{ \
    const int _qo = (u)*16; \
    h00[s] = ld16_sys(hq + q00 + _qo); \
    h01[s] = ld16_sys(hq + q00 + _qo + 8); \
    h10[s] = ld16_sys(hq + q10 + _qo); \
    h11[s] = ld16_sys(hq + q10 + _qo + 8); \
  }while(0)

  STAGEB(0,0); LOADH(0,0);
  STAGEB(1,1); LOADH(1,1);
  STAGEB(2,2); LOADH(2,2);

  for (int uu = 0; uu < 8; ++uu){
    #pragma unroll
    for (int j = 0; j < 4; ++j){
      const int u = uu*4 + j;
      const int rem = 31 - u;
      if (rem >= 2)      asm volatile("s_waitcnt vmcnt(20)" ::: "memory");
      else if (rem == 1) asm volatile("s_waitcnt vmcnt(10)" ::: "memory");
      else               asm volatile("s_waitcnt vmcnt(0)"  ::: "memory");
      asm volatile("s_barrier" ::: "memory");
      if (u + 3 < 32){ STAGEB(u+3, (j+3)&3); LOADH(u+3, (j+3)&3); }
      const char* bs = Bs + j*8192;
      const int swz0 = (rb0 & 7) << 4, swz1 = (rb1 & 7) << 4;
      bf16x8 b00 = *(const bf16x8*)(bs + rb0*128 + ((hi*16)      ^ swz0));
      bf16x8 b10 = *(const bf16x8*)(bs + rb1*128 + ((hi*16)      ^ swz1));
      bf16x8 b01 = *(const bf16x8*)(bs + rb0*128 + ((64 + hi*16) ^ swz0));
      bf16x8 b11 = *(const bf16x8*)(bs + rb1*128 + ((64 + hi*16) ^ swz1));
      acc[0][0] = __builtin_amdgcn_mfma_f32_16x16x32_bf16(h00[j], b00, acc[0][0], 0, 0, 0);
      acc[0][1] = __builtin_amdgcn_mfma_f32_16x16x32_bf16(h00[j], b10, acc[0][1], 0, 0, 0);
      acc[1][0] = __builtin_amdgcn_mfma_f32_16x16x32_bf16(h10[j], b00, acc[1][0], 0, 0, 0);
      acc[1][1] = __builtin_amdgcn_mfma_f32_16x16x32_bf16(h10[j], b10, acc[1][1], 0, 0, 0);
      acc[0][0] = __builtin_amdgcn_mfma_f32_16x16x32_bf16(h01[j], b01, acc[0][0], 0, 0, 0);
      acc[0][1] = __builtin_amdgcn_mfma_f32_16x16x32_bf16(h01[j], b11, acc[0][1], 0, 0, 0);
      acc[1][0] = __builtin_amdgcn_mfma_f32_16x16x32_bf16(h11[j], b01, acc[1][0], 0, 0, 0);
      acc[1][1] = __builtin_amdgcn_mfma_f32_16x16x32_bf16(h11[j], b11, acc[1][1], 0, 0, 0);
    }
  }
  #undef STAGEB
  #undef LOADH
}

// C/D layout (m89-verified): col = lane&15, row = (lane>>4)*4 + i.
// A-task epilogue: tanh + bf16 + system-scope (write-through) stores.
__device__ __forceinline__ void epi_h(const f32x4 acc[2][2], short* dst,
                                      const float* __restrict__ cv,
                                      int bm, int bn)
{
  const int lane = threadIdx.x & 63, wid = threadIdx.x >> 6;
  const int wm = (wid>>1)&1, wn = wid&1, r15 = lane&15, hi = lane>>4;
  #pragma unroll
  for (int mi = 0; mi < 2; ++mi)
    #pragma unroll
    for (int ni = 0; ni < 2; ++ni){
      int n = bn + wn*32 + ni*16 + r15;
      float cb = cv[n];
      #pragma unroll
      for (int i = 0; i < 4; ++i){
        int m = bm + wm*32 + mi*16 + hi*4 + i;
        short hv = f2bf(tanh_fast(acc[mi][ni][i] + cb));
        __hip_atomic_store(dst + (size_t)m*S_HIDDEN + n, hv,
                           __ATOMIC_RELAXED, __HIP_MEMORY_SCOPE_SYSTEM);
      }
    }
}

// B-task epilogue: plain f32 stores to d_out (host-visible at kernel end).
__device__ __forceinline__ void epi_out(const f32x4 acc[2][2], float* outp,
                                        const float* __restrict__ bfc,
                                        int bm, int bn)
{
  const int lane = threadIdx.x & 63, wid = threadIdx.x >> 6;
  const int wm = (wid>>1)&1, wn = wid&1, r15 = lane&15, hi = lane>>4;
  #pragma unroll
  for (int mi = 0; mi < 2; ++mi)
    #pragma unroll
    for (int ni = 0; ni < 2; ++ni){
      int n = bn + wn*32 + ni*16 + r15;
      float cb = bfc[n];
      #pragma unroll
      for (int i = 0; i < 4; ++i){
        int m = bm + wm*32 + mi*16 + hi*4 + i;
        outp[(size_t)m*(S_SEQ*S_INPUT) + n] = acc[mi][ni][i] + cb;
      }
    }
}

// ---------------------------------------------------------------------------
// Prologue kernels (unchanged)
// ---------------------------------------------------------------------------
__global__ __launch_bounds__(256) void k_build_wcat(const float* __restrict__ Wih,
                                                    const float* __restrict__ Whh,
                                                    short* __restrict__ Wcat)
{
  int j = blockIdx.x;
  for (int i = threadIdx.x; i < 3072; i += 256){
    float f = (i < 1024) ? Wih[(size_t)j*1024 + i] : Whh[(size_t)j*2048 + (i-1024)];
    Wcat[(size_t)j*3072 + i] = f2bf(f);
  }
}

__global__ __launch_bounds__(256) void k_build_acat(const float* __restrict__ x,
                                                    const float* __restrict__ h0,
                                                    short* __restrict__ Acat)
{
  int b = blockIdx.x;
  for (int i = threadIdx.x; i < 3072; i += 256){
    float f = (i < 1024) ? x[(size_t)b*1024 + i] : h0[(size_t)b*2048 + (i-1024)];
    Acat[(size_t)b*3072 + i] = f2bf(f);
  }
}

__global__ __launch_bounds__(256) void k_trans_wfc(const float* __restrict__ Wfc,
                                                   short* __restrict__ Wfcb,
                                                   short* __restrict__ WfcT)
{
  __shared__ float t[32][33];
  int i0 = blockIdx.x*32, k0 = blockIdx.y*32;
  int c = threadIdx.x & 31, r = threadIdx.x >> 5;
  #pragma unroll
  for (int rr = 0; rr < 4; ++rr){
    int i = i0 + r*4 + rr, k = k0 + c;
    float v = Wfc[(size_t)i*2048 + k];
    Wfcb[(size_t)i*2048 + k] = f2bf(v);
    t[r*4+rr][c] = v;
  }
  __syncthreads();
  #pragma unroll
  for (int rr = 0; rr < 4; ++rr){
    int k = k0 + r*4 + rr, i = i0 + c;
    WfcT[(size_t)k*1024 + i] = f2bf(t[c][r*4+rr]);
  }
}

__global__ __launch_bounds__(256) void k_cvec(const float* __restrict__ Wih,
                                              const float* __restrict__ bfc,
                                              const float* __restrict__ bih,
                                              const float* __restrict__ bhh,
                                              float* __restrict__ brnn,
                                              float* __restrict__ cvec)
{
  __shared__ float red[256];
  int j = blockIdx.x;
  float s = 0.f;
  for (int i = threadIdx.x; i < 1024; i += 256) s += Wih[(size_t)j*1024 + i]*bfc[i];
  red[threadIdx.x] = s; __syncthreads();
  for (int st = 128; st > 0; st >>= 1){
    if (threadIdx.x < st) red[threadIdx.x] += red[threadIdx.x+st];
    __syncthreads();
  }
  if (threadIdx.x == 0){
    float br = bih[j] + bhh[j];
    brnn[j] = br;
    cvec[j] = br + red[0];
  }
}

__global__ __launch_bounds__(256) void k_wcomb(const short* __restrict__ Wcat,
                                               const short* __restrict__ WfcT,
                                               const float* __restrict__ Whh,
                                               short* __restrict__ Wcomb)
{
  __shared__ char As[4*8192], Bs[4*8192];
  f32x4 acc[2][2] = {};
  int bid = blockIdx.x;
  int xcd = bid & 7, j = bid >> 3;
  int np = xcd*4 + (j & 3);
  int mp = j >> 2;
  int bm = mp*64, bn = np*64;
  gemm_core(Wcat, 3072, WfcT, 1024, bm, bn, 16, acc, As, Bs);
  const int lane = threadIdx.x & 63, wid = threadIdx.x >> 6;
  const int wm = (wid>>1)&1, wn = wid&1, r15 = lane&15, hi = lane>>4;
  #pragma unroll
  for (int mi = 0; mi < 2; ++mi)
    #pragma unroll
    for (int ni = 0; ni < 2; ++ni){
      int n = bn + wn*32 + ni*16 + r15;
      #pragma unroll
      for (int i = 0; i < 4; ++i){
        int m = bm + wm*32 + mi*16 + hi*4 + i;
        Wcomb[(size_t)m*2048 + n] = f2bf(acc[mi][ni][i] + Whh[(size_t)m*2048 + n]);
      }
    }
}

// ---------------------------------------------------------------------------
// Persistent step kernel.
// Blocks 0..127 (A): h_{t+1} = tanh(h_t @ Wcomb^T + cvec)   [coherent stores]
// Blocks 128..191 (B): out_{t-1} = h_t @ Wfc^T + b_fc       [plain stores]
// XCD-aware panel map (bid&7 = XCD): weights stay L2-resident (never
// invalidated); h crosses XCDs via system-scope atomics only.
// ---------------------------------------------------------------------------
__global__ __launch_bounds__(256) void k_persist(
    const short* __restrict__ Acat, const short* __restrict__ Wcat,
    const float* __restrict__ brnn,
    const short* __restrict__ Wcomb, const float* __restrict__ cvec,
    const short* __restrict__ Wfcb, const float* __restrict__ bfc,
    short* __restrict__ hb0, short* __restrict__ hb1,
    float* __restrict__ out, unsigned* __restrict__ bar)
{
  __shared__ char lds[65536];
  const int bid = blockIdx.x;

  const int axcd = bid & 7, aj = bid >> 3;
  const int abm = (aj >> 2) * 64;
  const int abn = (axcd*4 + (aj & 3)) * 64;
  const int b2 = bid - 128;
  const int bxcd = b2 & 7, bj = b2 >> 3;
  const int bbm = (bj >> 1) * 64;
  const int bbn = (bxcd*2 + (bj & 1)) * 64;

  int ep = 1;

  // ---- t = 0: h1 = tanh([x0|h0] @ [Wih|Whh]^T + brnn) (A-WGs, cached path) ----
  if (bid < 128){
    f32x4 acc[2][2] = {};
    gemm_core(Acat, 3072, Wcat, 3072, abm, abn, 48, acc, lds, lds + 32768);
    epi_h(acc, hb0, brnn, abm, abn);
  }
  step_barrier(bar, ep++, bid);

  const short* hc = hb0;
  short*       hn = hb1;
  for (int t = 1; t <= 255; ++t){
    if (bid < 128){
      f32x4 acc[2][2] = {};
      gemm_h(hc, Wcomb, abm, abn, acc, lds);
      epi_h(acc, hn, cvec, abm, abn);
    } else {
      f32x4 acc[2][2] = {};
      gemm_h(hc, Wfcb, bbm, bbn, acc, lds);
      epi_out(acc, out + (size_t)(t-1)*S_INPUT, bfc, bbm, bbn);
    }
    step_barrier(bar, ep++, bid);
    const short* tmp = hc; hc = hn; hn = (short*)tmp;
  }

  // ---- t = 256: out_255 = h_256 @ Wfc^T + b_fc (B-WGs) ----
  if (bid >= 128){
    f32x4 acc[2][2] = {};
    gemm_h(hc, Wfcb, bbm, bbn, acc, lds);
    epi_out(acc, out + (size_t)255*S_INPUT, bfc, bbm, bbn);
  }
}

// ---------------------------------------------------------------------------
extern "C" void kernel_launch(void* const* d_in, const int* in_sizes, int n_in,
                              void* d_out, int out_size, void* d_ws, size_t ws_size,
                              hipStream_t stream)
{
  const float* x   = (const float*)d_in[0];   // (256,1,1024)
  const float* h0  = (const float*)d_in[1];   // (1,256,2048)
  const float* Wih = (const float*)d_in[2];   // (2048,1024)
  const float* Whh = (const float*)d_in[3];   // (2048,2048)
  const float* bih = (const float*)d_in[4];   // (2048)
  const float* bhh = (const float*)d_in[5];   // (2048)
  const float* Wfc = (const float*)d_in[6];   // (1024,2048)
  const float* bfc = (const float*)d_in[7];   // (1024)
  float* out = (float*)d_out;                 // (256,256,1024) f32

  char* ws = (char*)d_ws;
  size_t off = 0;
  auto alloc = [&](size_t bytes) -> void* {
    void* p = ws + off;
    off += (bytes + 255) & ~(size_t)255;
    return p;
  };
  short* Wcat = (short*)alloc((size_t)2048*3072*2);   // [W_ih | W_hh] bf16
  short* Acat = (short*)alloc((size_t)256*3072*2);    // [x0 | h0] bf16
  short* WfcT = (short*)alloc((size_t)2048*1024*2);   // W_fc^T bf16
  short* Wfcb = (short*)alloc((size_t)1024*2048*2);   // W_fc bf16
  short* Wcb  = (short*)alloc((size_t)2048*2048*2);   // Wcomb bf16
  short* hb0  = (short*)alloc((size_t)256*2048*2);
  short* hb1  = (short*)alloc((size_t)256*2048*2);
  float* brnn = (float*)alloc(2048*4);
  float* cvec = (float*)alloc(2048*4);
  unsigned* bar = (unsigned*)alloc(16384);
  (void)ws_size; (void)in_sizes; (void)n_in; (void)out_size;

  // Zero barrier flags/gen (captured in graph; re-runs stay deterministic)
  hipMemsetAsync(bar, 0, 16384, stream);

  // Prologue
  k_build_wcat<<<2048, 256, 0, stream>>>(Wih, Whh, Wcat);
  k_build_acat<<<256, 256, 0, stream>>>(x, h0, Acat);
  k_trans_wfc<<<dim3(32, 64), 256, 0, stream>>>(Wfc, Wfcb, WfcT);
  k_cvec<<<2048, 256, 0, stream>>>(Wih, bfc, bih, bhh, brnn, cvec);
  k_wcomb<<<1024, 256, 0, stream>>>(Wcat, WfcT, Whh, Wcb);

  // One persistent cooperative kernel for all 256 steps
  void* args[] = { (void*)&Acat, (void*)&Wcat, (void*)&brnn,
                   (void*)&Wcb,  (void*)&cvec,
                   (void*)&Wfcb, (void*)&bfc,
                   (void*)&hb0,  (void*)&hb1,
                   (void*)&out,  (void*)&bar };
  hipLaunchCooperativeKernel((const void*)k_persist, dim3(NWG_P), dim3(256),
                             args, 0, stream);
}

// Round 6
// 7349.911 us; speedup vs baseline: 1.5386x; 1.5386x over previous
//
#include <hip/hip_runtime.h>
#include <hip/hip_bf16.h>
#include <stdint.h>

// Problem constants
#define S_INPUT  1024
#define S_HIDDEN 2048
#define S_SEQ    256
#define S_BATCH  256
#define NWG_P    192    // persistent grid: 128 A-task + 64 B-task WGs

typedef __attribute__((ext_vector_type(8))) short bf16x8;   // 8 bf16 = 4 VGPRs
typedef __attribute__((ext_vector_type(4))) float f32x4;    // MFMA accumulator

__device__ __forceinline__ short f2bf(float f){
  union { float f; unsigned u; } v; v.f = f;
  unsigned r = v.u + 0x7fffu + ((v.u >> 16) & 1u);   // round-nearest-even
  return (short)(r >> 16);
}

// tanh via one v_exp_f32 + v_rcp_f32; exact at saturation.
__device__ __forceinline__ float tanh_fast(float x){
  float e = __expf(2.0f * x);
  return 1.0f - 2.0f / (e + 1.0f);
}

// ---------------------------------------------------------------------------
// Flag-array grid barrier + once-per-step agent acquire.
// bar[0] = generation; bar[(1+wg)*16] = per-WG arrival flag (64B spacing).
// Arrival: RELEASE/SYSTEM store (compiler emits vmcnt drain + buffer_wbl2 +
// uncached store) -> every WG's h/out stores are at the coherence point
// BEFORE its flag is visible. WG0 gathers flags (uncached relaxed loads),
// publishes gen. All WGs then do ONE ACQUIRE/AGENT load -> buffer_inv sc1
// (drops stale clean h lines from local L1/L2). Nothing dirty can be lost:
// all dirty lines were written back by their owner's release fence first.
// Data loads stay fully cached -> L2 dedupe + short latency (R4's fix).
// ---------------------------------------------------------------------------
__device__ __forceinline__ void step_barrier(unsigned* bar, int ep, int bid)
{
  __syncthreads();
  const int tid = threadIdx.x;
  if (tid == 0){
    __hip_atomic_store(bar + (size_t)(1 + bid)*16, (unsigned)ep,
                       __ATOMIC_RELEASE, __HIP_MEMORY_SCOPE_SYSTEM);
  }
  if (bid == 0){
    for (;;){
      int ok = 1;
      if (tid >= 1 && tid < NWG_P){
        unsigned v = __hip_atomic_load(bar + (size_t)(1 + tid)*16,
                                       __ATOMIC_RELAXED, __HIP_MEMORY_SCOPE_SYSTEM);
        ok = (v >= (unsigned)ep);
      }
      if (__syncthreads_and(ok)) break;
      __builtin_amdgcn_s_sleep(1);
    }
    if (tid == 0)
      __hip_atomic_store(bar, (unsigned)ep, __ATOMIC_RELEASE, __HIP_MEMORY_SCOPE_SYSTEM);
  }
  if (tid == 0){
    while (__hip_atomic_load(bar, __ATOMIC_RELAXED, __HIP_MEMORY_SCOPE_SYSTEM) < (unsigned)ep)
      __builtin_amdgcn_s_sleep(1);
    // agent acquire: buffer_inv sc1 (L1+L2) -> other XCDs' h becomes visible
    (void)__hip_atomic_load(bar, __ATOMIC_ACQUIRE, __HIP_MEMORY_SCOPE_AGENT);
    asm volatile("s_waitcnt vmcnt(0)" ::: "memory");   // inv retired before peers load
  }
  __syncthreads();
}

// ---------------------------------------------------------------------------
// 64x64x(K) bf16 GEMM core, B^T layout: out[m][n] = sum_k A[m][k]*B[n][k].
// 4 waves (2x2), each owns a 32x32 sub-tile. 4-deep LDS pipeline, counted
// vmcnt, raw s_barrier (no vmcnt drain). Cached loads (L2/L3 dedupe).
// ---------------------------------------------------------------------------
__device__ __forceinline__ void gemm_core(const short* __restrict__ A, int lda,
                                          const short* __restrict__ B, int ldb,
                                          int bm, int bn, int ktiles,
                                          f32x4 acc[2][2], char* As, char* Bs)
{
  const int tid  = threadIdx.x;
  const int lane = tid & 63;
  const int wid  = tid >> 6;
  const int wm   = (wid >> 1) & 1;
  const int wn   = wid & 1;
  const int r15  = lane & 15;
  const int hi   = lane >> 4;
  const int ra0 = wm*32 + r15,  ra1 = ra0 + 16;
  const int rb0 = wn*32 + r15,  rb1 = rb0 + 16;

  const int c0 = tid, c1 = tid + 256;
  const int r0 = c0 >> 3, r1 = c1 >> 3;
  const int e0 = ((((c0 & 7) << 4) ^ ((r0 & 7) << 4)) >> 1);  // inverse swizzle
  const int e1 = ((((c1 & 7) << 4) ^ ((r1 & 7) << 4)) >> 1);
  const short* pa0 = A + (size_t)(bm + r0)*lda + e0;
  const short* pa1 = A + (size_t)(bm + r1)*lda + e1;
  const short* pb0 = B + (size_t)(bn + r0)*ldb + e0;
  const short* pb1 = B + (size_t)(bn + r1)*ldb + e1;
  char* la0 = As + c0*16;  char* la1 = As + c1*16;
  char* lb0 = Bs + c0*16;  char* lb1 = Bs + c1*16;

  #define STAGE4(kt, s) do { \
    const int _ko = (kt)*64; const int _so = (s)*8192; \
    __builtin_amdgcn_global_load_lds((const __attribute__((address_space(1))) void*)(pa0 + _ko), \
                                     (__attribute__((address_space(3))) void*)(la0 + _so), 16, 0, 0); \
    __builtin_amdgcn_global_load_lds((const __attribute__((address_space(1))) void*)(pb0 + _ko), \
                                     (__attribute__((address_space(3))) void*)(lb0 + _so), 16, 0, 0); \
    __builtin_amdgcn_global_load_lds((const __attribute__((address_space(1))) void*)(pa1 + _ko), \
                                     (__attribute__((address_space(3))) void*)(la1 + _so), 16, 0, 0); \
    __builtin_amdgcn_global_load_lds((const __attribute__((address_space(1))) void*)(pb1 + _ko), \
                                     (__attribute__((address_space(3))) void*)(lb1 + _so), 16, 0, 0); \
  } while (0)

  STAGE4(0, 0);
  if (ktiles > 1) STAGE4(1, 1);
  if (ktiles > 2) STAGE4(2, 2);

  for (int t = 0; t < ktiles; ++t){
    const int rem = ktiles - 1 - t;
    if (rem >= 2)      asm volatile("s_waitcnt vmcnt(8)" ::: "memory");
    else if (rem == 1) asm volatile("s_waitcnt vmcnt(4)" ::: "memory");
    else               asm volatile("s_waitcnt vmcnt(0)" ::: "memory");
    asm volatile("s_barrier" ::: "memory");
    if (t + 3 < ktiles) STAGE4(t + 3, (t + 3) & 3);
    const char* as = As + (t & 3)*8192;
    const char* bs = Bs + (t & 3)*8192;
    #pragma unroll
    for (int kk = 0; kk < 2; ++kk){
      const int kb = kk*64 + hi*16;
      bf16x8 a0 = *(const bf16x8*)(as + ra0*128 + (kb ^ ((ra0 & 7) << 4)));
      bf16x8 a1 = *(const bf16x8*)(as + ra1*128 + (kb ^ ((ra1 & 7) << 4)));
      bf16x8 b0 = *(const bf16x8*)(bs + rb0*128 + (kb ^ ((rb0 & 7) << 4)));
      bf16x8 b1 = *(const bf16x8*)(bs + rb1*128 + (kb ^ ((rb1 & 7) << 4)));
      acc[0][0] = __builtin_amdgcn_mfma_f32_16x16x32_bf16(a0, b0, acc[0][0], 0, 0, 0);
      acc[0][1] = __builtin_amdgcn_mfma_f32_16x16x32_bf16(a0, b1, acc[0][1], 0, 0, 0);
      acc[1][0] = __builtin_amdgcn_mfma_f32_16x16x32_bf16(a1, b0, acc[1][0], 0, 0, 0);
      acc[1][1] = __builtin_amdgcn_mfma_f32_16x16x32_bf16(a1, b1, acc[1][1], 0, 0, 0);
    }
  }
  #undef STAGE4
}

// C/D layout (m89-verified): col = lane&15, row = (lane>>4)*4 + i.
// A-task epilogue: tanh + bf16, plain cached stores (flushed by the
// release fence in step_barrier before the flag becomes visible).
__device__ __forceinline__ void epi_h(const f32x4 acc[2][2], short* dst,
                                      const float* __restrict__ cv,
                                      int bm, int bn)
{
  const int lane = threadIdx.x & 63, wid = threadIdx.x >> 6;
  const int wm = (wid>>1)&1, wn = wid&1, r15 = lane&15, hi = lane>>4;
  #pragma unroll
  for (int mi = 0; mi < 2; ++mi)
    #pragma unroll
    for (int ni = 0; ni < 2; ++ni){
      int n = bn + wn*32 + ni*16 + r15;
      float cb = cv[n];
      #pragma unroll
      for (int i = 0; i < 4; ++i){
        int m = bm + wm*32 + mi*16 + hi*4 + i;
        dst[(size_t)m*S_HIDDEN + n] = f2bf(tanh_fast(acc[mi][ni][i] + cb));
      }
    }
}

// B-task epilogue: plain f32 stores to d_out.
__device__ __forceinline__ void epi_out(const f32x4 acc[2][2], float* outp,
                                        const float* __restrict__ bfc,
                                        int bm, int bn)
{
  const int lane = threadIdx.x & 63, wid = threadIdx.x >> 6;
  const int wm = (wid>>1)&1, wn = wid&1, r15 = lane&15, hi = lane>>4;
  #pragma unroll
  for (int mi = 0; mi < 2; ++mi)
    #pragma unroll
    for (int ni = 0; ni < 2; ++ni){
      int n = bn + wn*32 + ni*16 + r15;
      float cb = bfc[n];
      #pragma unroll
      for (int i = 0; i < 4; ++i){
        int m = bm + wm*32 + mi*16 + hi*4 + i;
        outp[(size_t)m*(S_SEQ*S_INPUT) + n] = acc[mi][ni][i] + cb;
      }
    }
}

// ---------------------------------------------------------------------------
// Prologue kernels (unchanged)
// ---------------------------------------------------------------------------
__global__ __launch_bounds__(256) void k_build_wcat(const float* __restrict__ Wih,
                                                    const float* __restrict__ Whh,
                                                    short* __restrict__ Wcat)
{
  int j = blockIdx.x;
  for (int i = threadIdx.x; i < 3072; i += 256){
    float f = (i < 1024) ? Wih[(size_t)j*1024 + i] : Whh[(size_t)j*2048 + (i-1024)];
    Wcat[(size_t)j*3072 + i] = f2bf(f);
  }
}

__global__ __launch_bounds__(256) void k_build_acat(const float* __restrict__ x,
                                                    const float* __restrict__ h0,
                                                    short* __restrict__ Acat)
{
  int b = blockIdx.x;
  for (int i = threadIdx.x; i < 3072; i += 256){
    float f = (i < 1024) ? x[(size_t)b*1024 + i] : h0[(size_t)b*2048 + (i-1024)];
    Acat[(size_t)b*3072 + i] = f2bf(f);
  }
}

__global__ __launch_bounds__(256) void k_trans_wfc(const float* __restrict__ Wfc,
                                                   short* __restrict__ Wfcb,
                                                   short* __restrict__ WfcT)
{
  __shared__ float t[32][33];
  int i0 = blockIdx.x*32, k0 = blockIdx.y*32;
  int c = threadIdx.x & 31, r = threadIdx.x >> 5;
  #pragma unroll
  for (int rr = 0; rr < 4; ++rr){
    int i = i0 + r*4 + rr, k = k0 + c;
    float v = Wfc[(size_t)i*2048 + k];
    Wfcb[(size_t)i*2048 + k] = f2bf(v);
    t[r*4+rr][c] = v;
  }
  __syncthreads();
  #pragma unroll
  for (int rr = 0; rr < 4; ++rr){
    int k = k0 + r*4 + rr, i = i0 + c;
    WfcT[(size_t)k*1024 + i] = f2bf(t[c][r*4+rr]);
  }
}

__global__ __launch_bounds__(256) void k_cvec(const float* __restrict__ Wih,
                                              const float* __restrict__ bfc,
                                              const float* __restrict__ bih,
                                              const float* __restrict__ bhh,
                                              float* __restrict__ brnn,
                                              float* __restrict__ cvec)
{
  __shared__ float red[256];
  int j = blockIdx.x;
  float s = 0.f;
  for (int i = threadIdx.x; i < 1024; i += 256) s += Wih[(size_t)j*1024 + i]*bfc[i];
  red[threadIdx.x] = s; __syncthreads();
  for (int st = 128; st > 0; st >>= 1){
    if (threadIdx.x < st) red[threadIdx.x] += red[threadIdx.x+st];
    __syncthreads();
  }
  if (threadIdx.x == 0){
    float br = bih[j] + bhh[j];
    brnn[j] = br;
    cvec[j] = br + red[0];
  }
}

__global__ __launch_bounds__(256) void k_wcomb(const short* __restrict__ Wcat,
                                               const short* __restrict__ WfcT,
                                               const float* __restrict__ Whh,
                                               short* __restrict__ Wcomb)
{
  __shared__ char As[4*8192], Bs[4*8192];
  f32x4 acc[2][2] = {};
  int bid = blockIdx.x;
  int xcd = bid & 7, j = bid >> 3;
  int np = xcd*4 + (j & 3);
  int mp = j >> 2;
  int bm = mp*64, bn = np*64;
  gemm_core(Wcat, 3072, WfcT, 1024, bm, bn, 16, acc, As, Bs);
  const int lane = threadIdx.x & 63, wid = threadIdx.x >> 6;
  const int wm = (wid>>1)&1, wn = wid&1, r15 = lane&15, hi = lane>>4;
  #pragma unroll
  for (int mi = 0; mi < 2; ++mi)
    #pragma unroll
    for (int ni = 0; ni < 2; ++ni){
      int n = bn + wn*32 + ni*16 + r15;
      #pragma unroll
      for (int i = 0; i < 4; ++i){
        int m = bm + wm*32 + mi*16 + hi*4 + i;
        Wcomb[(size_t)m*2048 + n] = f2bf(acc[mi][ni][i] + Whh[(size_t)m*2048 + n]);
      }
    }
}

// ---------------------------------------------------------------------------
// Persistent step kernel.
// Blocks 0..127 (A): h_{t+1} = tanh(h_t @ Wcomb^T + cvec)
// Blocks 128..191 (B): out_{t-1} = h_t @ Wfc^T + b_fc
// Cached loads everywhere; cross-XCD h visibility via the per-step
// release(wbl2)/acquire(inv) pair in step_barrier. XCD-aware panel map
// (bid&7 = XCD) keeps per-XCD refetch (post-inv) to ~2.5MB from warm L3.
// ---------------------------------------------------------------------------
__global__ __launch_bounds__(256) void k_persist(
    const short* __restrict__ Acat, const short* __restrict__ Wcat,
    const float* __restrict__ brnn,
    const short* __restrict__ Wcomb, const float* __restrict__ cvec,
    const short* __restrict__ Wfcb, const float* __restrict__ bfc,
    short* __restrict__ hb0, short* __restrict__ hb1,
    float* __restrict__ out, unsigned* __restrict__ bar)
{
  __shared__ char lds[65536];
  const int bid = blockIdx.x;

  const int axcd = bid & 7, aj = bid >> 3;
  const int abm = (aj >> 2) * 64;
  const int abn = (axcd*4 + (aj & 3)) * 64;
  const int b2 = bid - 128;
  const int bxcd = b2 & 7, bj = b2 >> 3;
  const int bbm = (bj >> 1) * 64;
  const int bbn = (bxcd*2 + (bj & 1)) * 64;

  int ep = 1;

  // ---- t = 0: h1 = tanh([x0|h0] @ [Wih|Whh]^T + brnn) ----
  if (bid < 128){
    f32x4 acc[2][2] = {};
    gemm_core(Acat, 3072, Wcat, 3072, abm, abn, 48, acc, lds, lds + 32768);
    epi_h(acc, hb0, brnn, abm, abn);
  }
  step_barrier(bar, ep++, bid);

  const short* hc = hb0;
  short*       hn = hb1;
  for (int t = 1; t <= 255; ++t){
    if (bid < 128){
      f32x4 acc[2][2] = {};
      gemm_core(hc, S_HIDDEN, Wcomb, S_HIDDEN, abm, abn, 32, acc, lds, lds + 32768);
      epi_h(acc, hn, cvec, abm, abn);
    } else {
      f32x4 acc[2][2] = {};
      gemm_core(hc, S_HIDDEN, Wfcb, S_HIDDEN, bbm, bbn, 32, acc, lds, lds + 32768);
      epi_out(acc, out + (size_t)(t-1)*S_INPUT, bfc, bbm, bbn);
    }
    step_barrier(bar, ep++, bid);
    const short* tmp = hc; hc = hn; hn = (short*)tmp;
  }

  // ---- t = 256: out_255 = h_256 @ Wfc^T + b_fc (B-WGs) ----
  if (bid >= 128){
    f32x4 acc[2][2] = {};
    gemm_core(hc, S_HIDDEN, Wfcb, S_HIDDEN, bbm, bbn, 32, acc, lds, lds + 32768);
    epi_out(acc, out + (size_t)255*S_INPUT, bfc, bbm, bbn);
  }
}

// ---------------------------------------------------------------------------
extern "C" void kernel_launch(void* const* d_in, const int* in_sizes, int n_in,
                              void* d_out, int out_size, void* d_ws, size_t ws_size,
                              hipStream_t stream)
{
  const float* x   = (const float*)d_in[0];   // (256,1,1024)
  const float* h0  = (const float*)d_in[1];   // (1,256,2048)
  const float* Wih = (const float*)d_in[2];   // (2048,1024)
  const float* Whh = (const float*)d_in[3];   // (2048,2048)
  const float* bih = (const float*)d_in[4];   // (2048)
  const float* bhh = (const float*)d_in[5];   // (2048)
  const float* Wfc = (const float*)d_in[6];   // (1024,2048)
  const float* bfc = (const float*)d_in[7];   // (1024)
  float* out = (float*)d_out;                 // (256,256,1024) f32

  char* ws = (char*)d_ws;
  size_t off = 0;
  auto alloc = [&](size_t bytes) -> void* {
    void* p = ws + off;
    off += (bytes + 255) & ~(size_t)255;
    return p;
  };
  short* Wcat = (short*)alloc((size_t)2048*3072*2);   // [W_ih | W_hh] bf16
  short* Acat = (short*)alloc((size_t)256*3072*2);    // [x0 | h0] bf16
  short* WfcT = (short*)alloc((size_t)2048*1024*2);   // W_fc^T bf16
  short* Wfcb = (short*)alloc((size_t)1024*2048*2);   // W_fc bf16
  short* Wcb  = (short*)alloc((size_t)2048*2048*2);   // Wcomb bf16
  short* hb0  = (short*)alloc((size_t)256*2048*2);
  short* hb1  = (short*)alloc((size_t)256*2048*2);
  float* brnn = (float*)alloc(2048*4);
  float* cvec = (float*)alloc(2048*4);
  unsigned* bar = (unsigned*)alloc(16384);
  (void)ws_size; (void)in_sizes; (void)n_in; (void)out_size;

  // Zero barrier flags/gen (captured in graph; re-runs stay deterministic)
  hipMemsetAsync(bar, 0, 16384, stream);

  // Prologue
  k_build_wcat<<<2048, 256, 0, stream>>>(Wih, Whh, Wcat);
  k_build_acat<<<256, 256, 0, stream>>>(x, h0, Acat);
  k_trans_wfc<<<dim3(32, 64), 256, 0, stream>>>(Wfc, Wfcb, WfcT);
  k_cvec<<<2048, 256, 0, stream>>>(Wih, bfc, bih, bhh, brnn, cvec);
  k_wcomb<<<1024, 256, 0, stream>>>(Wcat, WfcT, Whh, Wcb);

  // One persistent cooperative kernel for all 256 steps
  void* args[] = { (void*)&Acat, (void*)&Wcat, (void*)&brnn,
                   (void*)&Wcb,  (void*)&cvec,
                   (void*)&Wfcb, (void*)&bfc,
                   (void*)&hb0,  (void*)&hb1,
                   (void*)&out,  (void*)&bar };
  hipLaunchCooperativeKernel((const void*)k_persist, dim3(NWG_P), dim3(256),
                             args, 0, stream);
}

// Round 7
// 5800.085 us; speedup vs baseline: 1.9497x; 1.2672x over previous
//
#include <hip/hip_runtime.h>
#include <hip/hip_bf16.h>
#include <stdint.h>

// Problem constants
#define S_INPUT  1024
#define S_HIDDEN 2048
#define S_SEQ    256
#define S_BATCH  256
#define NWG_P    192    // persistent grid: 128 A-task + 64 B-task WGs

typedef __attribute__((ext_vector_type(8))) short bf16x8;   // 8 bf16 = 4 VGPRs
typedef __attribute__((ext_vector_type(4))) float f32x4;    // MFMA accumulator

// CPol bits (SIDefines.h): GLC=1 SLC=2 DLC=4 SCC=16; gfx94x/gfx950: SC0=GLC, SC1=SCC.
#define AUX_CACHED 0
#define AUX_SYS    17   // SC0|SC1: bypass L1+L2, read at coherence point

__device__ __forceinline__ short f2bf(float f){
  union { float f; unsigned u; } v; v.f = f;
  unsigned r = v.u + 0x7fffu + ((v.u >> 16) & 1u);   // round-nearest-even
  return (short)(r >> 16);
}

// tanh via one v_exp_f32 + v_rcp_f32; exact at saturation.
__device__ __forceinline__ float tanh_fast(float x){
  float e = __expf(2.0f * x);
  return 1.0f - 2.0f / (e + 1.0f);
}

// ---------------------------------------------------------------------------
// Flag-array grid barrier, NO cache maintenance (no wbl2, no inv).
// bar[0] = generation; bar[(1+wg)*16] = per-WG arrival flag (64B spacing).
// All flag/gen traffic is relaxed SYSTEM-scope (uncached). Each WG drains
// vmcnt(0) before flagging -> its h stores (uncached, system-scope) are at
// the coherence point before the flag is visible. Readers fetch h with
// SC0|SC1 loads (L2-bypassing), so no invalidation is ever needed and
// weights stay L2-resident for all 256 steps.
// ---------------------------------------------------------------------------
__device__ __forceinline__ void step_barrier(unsigned* bar, int ep, int bid)
{
  asm volatile("s_waitcnt vmcnt(0) lgkmcnt(0)" ::: "memory");
  __syncthreads();
  const int tid = threadIdx.x;
  if (tid == 0)
    __hip_atomic_store(bar + (size_t)(1 + bid)*16, (unsigned)ep,
                       __ATOMIC_RELAXED, __HIP_MEMORY_SCOPE_SYSTEM);
  if (bid == 0){
    for (;;){
      int ok = 1;
      if (tid >= 1 && tid < NWG_P){
        unsigned v = __hip_atomic_load(bar + (size_t)(1 + tid)*16,
                                       __ATOMIC_RELAXED, __HIP_MEMORY_SCOPE_SYSTEM);
        ok = (v >= (unsigned)ep);
      }
      if (__syncthreads_and(ok)) break;
      __builtin_amdgcn_s_sleep(1);
    }
    if (tid == 0)
      __hip_atomic_store(bar, (unsigned)ep,
                         __ATOMIC_RELAXED, __HIP_MEMORY_SCOPE_SYSTEM);
  }
  if (tid == 0){
    while (__hip_atomic_load(bar, __ATOMIC_RELAXED, __HIP_MEMORY_SCOPE_SYSTEM) < (unsigned)ep)
      __builtin_amdgcn_s_sleep(1);
  }
  __syncthreads();
}

// ---------------------------------------------------------------------------
// 64x64x(K) bf16 GEMM core, B^T layout: out[m][n] = sum_k A[m][k]*B[n][k].
// 4 waves (2x2), each owns a 32x32 sub-tile. 6-slot LDS ring, prefetch
// distance 5 (~1200cy cover for L3-latency A loads), counted vmcnt, raw
// s_barrier. AUXA selects the A-operand cache policy: AUX_SYS for h
// (L2-bypassing, always fresh), AUX_CACHED for prologue inputs.
// B always cached (L2-resident weights).
// ---------------------------------------------------------------------------
template<int AUXA>
__device__ __forceinline__ void gemm_core(const short* __restrict__ A, int lda,
                                          const short* __restrict__ B, int ldb,
                                          int bm, int bn, int ktiles,
                                          f32x4 acc[2][2], char* As, char* Bs)
{
  const int tid  = threadIdx.x;
  const int lane = tid & 63;
  const int wid  = tid >> 6;
  const int wm   = (wid >> 1) & 1;
  const int wn   = wid & 1;
  const int r15  = lane & 15;
  const int hi   = lane >> 4;
  const int ra0 = wm*32 + r15,  ra1 = ra0 + 16;
  const int rb0 = wn*32 + r15,  rb1 = rb0 + 16;

  const int c0 = tid, c1 = tid + 256;
  const int r0 = c0 >> 3, r1 = c1 >> 3;
  const int e0 = ((((c0 & 7) << 4) ^ ((r0 & 7) << 4)) >> 1);  // inverse swizzle
  const int e1 = ((((c1 & 7) << 4) ^ ((r1 & 7) << 4)) >> 1);
  const short* pa0 = A + (size_t)(bm + r0)*lda + e0;
  const short* pa1 = A + (size_t)(bm + r1)*lda + e1;
  const short* pb0 = B + (size_t)(bn + r0)*ldb + e0;
  const short* pb1 = B + (size_t)(bn + r1)*ldb + e1;
  char* la0 = As + c0*16;  char* la1 = As + c1*16;
  char* lb0 = Bs + c0*16;  char* lb1 = Bs + c1*16;

  // 4 vmcnt entries per STAGE (2 A + 2 B).
  #define STAGE6(kt, s) do { \
    const int _ko = (kt)*64; const int _so = (s)*8192; \
    __builtin_amdgcn_global_load_lds((const __attribute__((address_space(1))) void*)(pa0 + _ko), \
                                     (__attribute__((address_space(3))) void*)(la0 + _so), 16, 0, AUXA); \
    __builtin_amdgcn_global_load_lds((const __attribute__((address_space(1))) void*)(pb0 + _ko), \
                                     (__attribute__((address_space(3))) void*)(lb0 + _so), 16, 0, AUX_CACHED); \
    __builtin_amdgcn_global_load_lds((const __attribute__((address_space(1))) void*)(pa1 + _ko), \
                                     (__attribute__((address_space(3))) void*)(la1 + _so), 16, 0, AUXA); \
    __builtin_amdgcn_global_load_lds((const __attribute__((address_space(1))) void*)(pb1 + _ko), \
                                     (__attribute__((address_space(3))) void*)(lb1 + _so), 16, 0, AUX_CACHED); \
  } while (0)

  STAGE6(0, 0);
  STAGE6(1, 1);
  STAGE6(2, 2);
  STAGE6(3, 3);
  STAGE6(4, 4);

  int sNext = 5;   // LDS slot for stage t+5
  int sCur  = 0;   // LDS slot for stage t
  for (int t = 0; t < ktiles; ++t){
    const int rem = ktiles - 1 - t;
    if (rem >= 4)      asm volatile("s_waitcnt vmcnt(16)" ::: "memory");
    else if (rem == 3) asm volatile("s_waitcnt vmcnt(12)" ::: "memory");
    else if (rem == 2) asm volatile("s_waitcnt vmcnt(8)"  ::: "memory");
    else if (rem == 1) asm volatile("s_waitcnt vmcnt(4)"  ::: "memory");
    else               asm volatile("s_waitcnt vmcnt(0)"  ::: "memory");
    asm volatile("s_barrier" ::: "memory");   // raw: prefetch stays in flight
    if (t + 5 < ktiles) STAGE6(t + 5, sNext);
    sNext = (sNext == 5) ? 0 : sNext + 1;
    const char* as = As + sCur*8192;
    const char* bs = Bs + sCur*8192;
    sCur = (sCur == 5) ? 0 : sCur + 1;
    #pragma unroll
    for (int kk = 0; kk < 2; ++kk){
      const int kb = kk*64 + hi*16;
      bf16x8 a0 = *(const bf16x8*)(as + ra0*128 + (kb ^ ((ra0 & 7) << 4)));
      bf16x8 a1 = *(const bf16x8*)(as + ra1*128 + (kb ^ ((ra1 & 7) << 4)));
      bf16x8 b0 = *(const bf16x8*)(bs + rb0*128 + (kb ^ ((rb0 & 7) << 4)));
      bf16x8 b1 = *(const bf16x8*)(bs + rb1*128 + (kb ^ ((rb1 & 7) << 4)));
      acc[0][0] = __builtin_amdgcn_mfma_f32_16x16x32_bf16(a0, b0, acc[0][0], 0, 0, 0);
      acc[0][1] = __builtin_amdgcn_mfma_f32_16x16x32_bf16(a0, b1, acc[0][1], 0, 0, 0);
      acc[1][0] = __builtin_amdgcn_mfma_f32_16x16x32_bf16(a1, b0, acc[1][0], 0, 0, 0);
      acc[1][1] = __builtin_amdgcn_mfma_f32_16x16x32_bf16(a1, b1, acc[1][1], 0, 0, 0);
    }
  }
  #undef STAGE6
}

// C/D layout (m89-verified): col = lane&15, row = (lane>>4)*4 + i.
// A-task epilogue: tanh + bf16, SYSTEM-scope relaxed (uncached) stores ->
// h lands at the coherence point; L2 never dirtied (no wbl2 ever needed).
__device__ __forceinline__ void epi_h(const f32x4 acc[2][2], short* dst,
                                      const float* __restrict__ cv,
                                      int bm, int bn)
{
  const int lane = threadIdx.x & 63, wid = threadIdx.x >> 6;
  const int wm = (wid>>1)&1, wn = wid&1, r15 = lane&15, hi = lane>>4;
  #pragma unroll
  for (int mi = 0; mi < 2; ++mi)
    #pragma unroll
    for (int ni = 0; ni < 2; ++ni){
      int n = bn + wn*32 + ni*16 + r15;
      float cb = cv[n];
      #pragma unroll
      for (int i = 0; i < 4; ++i){
        int m = bm + wm*32 + mi*16 + hi*4 + i;
        short hv = f2bf(tanh_fast(acc[mi][ni][i] + cb));
        __hip_atomic_store(dst + (size_t)m*S_HIDDEN + n, hv,
                           __ATOMIC_RELAXED, __HIP_MEMORY_SCOPE_SYSTEM);
      }
    }
}

// B-task epilogue: plain f32 stores to d_out (implicit kernel-end release
// makes them host-visible).
__device__ __forceinline__ void epi_out(const f32x4 acc[2][2], float* outp,
                                        const float* __restrict__ bfc,
                                        int bm, int bn)
{
  const int lane = threadIdx.x & 63, wid = threadIdx.x >> 6;
  const int wm = (wid>>1)&1, wn = wid&1, r15 = lane&15, hi = lane>>4;
  #pragma unroll
  for (int mi = 0; mi < 2; ++mi)
    #pragma unroll
    for (int ni = 0; ni < 2; ++ni){
      int n = bn + wn*32 + ni*16 + r15;
      float cb = bfc[n];
      #pragma unroll
      for (int i = 0; i < 4; ++i){
        int m = bm + wm*32 + mi*16 + hi*4 + i;
        outp[(size_t)m*(S_SEQ*S_INPUT) + n] = acc[mi][ni][i] + cb;
      }
    }
}

// ---------------------------------------------------------------------------
// Prologue kernels
// ---------------------------------------------------------------------------
__global__ __launch_bounds__(256) void k_build_wcat(const float* __restrict__ Wih,
                                                    const float* __restrict__ Whh,
                                                    short* __restrict__ Wcat)
{
  int j = blockIdx.x;
  for (int i = threadIdx.x; i < 3072; i += 256){
    float f = (i < 1024) ? Wih[(size_t)j*1024 + i] : Whh[(size_t)j*2048 + (i-1024)];
    Wcat[(size_t)j*3072 + i] = f2bf(f);
  }
}

__global__ __launch_bounds__(256) void k_build_acat(const float* __restrict__ x,
                                                    const float* __restrict__ h0,
                                                    short* __restrict__ Acat)
{
  int b = blockIdx.x;
  for (int i = threadIdx.x; i < 3072; i += 256){
    float f = (i < 1024) ? x[(size_t)b*1024 + i] : h0[(size_t)b*2048 + (i-1024)];
    Acat[(size_t)b*3072 + i] = f2bf(f);
  }
}

__global__ __launch_bounds__(256) void k_trans_wfc(const float* __restrict__ Wfc,
                                                   short* __restrict__ Wfcb,
                                                   short* __restrict__ WfcT)
{
  __shared__ float t[32][33];
  int i0 = blockIdx.x*32, k0 = blockIdx.y*32;
  int c = threadIdx.x & 31, r = threadIdx.x >> 5;
  #pragma unroll
  for (int rr = 0; rr < 4; ++rr){
    int i = i0 + r*4 + rr, k = k0 + c;
    float v = Wfc[(size_t)i*2048 + k];
    Wfcb[(size_t)i*2048 + k] = f2bf(v);
    t[r*4+rr][c] = v;
  }
  __syncthreads();
  #pragma unroll
  for (int rr = 0; rr < 4; ++rr){
    int k = k0 + r*4 + rr, i = i0 + c;
    WfcT[(size_t)k*1024 + i] = f2bf(t[c][r*4+rr]);
  }
}

__global__ __launch_bounds__(256) void k_cvec(const float* __restrict__ Wih,
                                              const float* __restrict__ bfc,
                                              const float* __restrict__ bih,
                                              const float* __restrict__ bhh,
                                              float* __restrict__ brnn,
                                              float* __restrict__ cvec)
{
  __shared__ float red[256];
  int j = blockIdx.x;
  float s = 0.f;
  for (int i = threadIdx.x; i < 1024; i += 256) s += Wih[(size_t)j*1024 + i]*bfc[i];
  red[threadIdx.x] = s; __syncthreads();
  for (int st = 128; st > 0; st >>= 1){
    if (threadIdx.x < st) red[threadIdx.x] += red[threadIdx.x+st];
    __syncthreads();
  }
  if (threadIdx.x == 0){
    float br = bih[j] + bhh[j];
    brnn[j] = br;
    cvec[j] = br + red[0];
  }
}

__global__ __launch_bounds__(256) void k_wcomb(const short* __restrict__ Wcat,
                                               const short* __restrict__ WfcT,
                                               const float* __restrict__ Whh,
                                               short* __restrict__ Wcomb)
{
  __shared__ char As[6*8192], Bs[6*8192];
  f32x4 acc[2][2] = {};
  int bid = blockIdx.x;
  int xcd = bid & 7, j = bid >> 3;
  int np = xcd*4 + (j & 3);
  int mp = j >> 2;
  int bm = mp*64, bn = np*64;
  gemm_core<AUX_CACHED>(Wcat, 3072, WfcT, 1024, bm, bn, 16, acc, As, Bs);
  const int lane = threadIdx.x & 63, wid = threadIdx.x >> 6;
  const int wm = (wid>>1)&1, wn = wid&1, r15 = lane&15, hi = lane>>4;
  #pragma unroll
  for (int mi = 0; mi < 2; ++mi)
    #pragma unroll
    for (int ni = 0; ni < 2; ++ni){
      int n = bn + wn*32 + ni*16 + r15;
      #pragma unroll
      for (int i = 0; i < 4; ++i){
        int m = bm + wm*32 + mi*16 + hi*4 + i;
        Wcomb[(size_t)m*2048 + n] = f2bf(acc[mi][ni][i] + Whh[(size_t)m*2048 + n]);
      }
    }
}

// ---------------------------------------------------------------------------
// Persistent step kernel.
// Blocks 0..127 (A): h_{t+1} = tanh(h_t @ Wcomb^T + cvec)   [uncached h store]
// Blocks 128..191 (B): out_{t-1} = h_t @ Wfc^T + b_fc       [plain stores]
// h reads: SC0|SC1 global_load_lds (fresh, L2-bypassing); weights: cached,
// L2-resident all 256 steps (never invalidated). XCD-aware panel map
// (bid&7 = XCD) keeps per-XCD weight slice at 1.5MB < 4MB L2.
// ---------------------------------------------------------------------------
__global__ __launch_bounds__(256) void k_persist(
    const short* __restrict__ Acat, const short* __restrict__ Wcat,
    const float* __restrict__ brnn,
    const short* __restrict__ Wcomb, const float* __restrict__ cvec,
    const short* __restrict__ Wfcb, const float* __restrict__ bfc,
    short* __restrict__ hb0, short* __restrict__ hb1,
    float* __restrict__ out, unsigned* __restrict__ bar)
{
  __shared__ char As[6*8192], Bs[6*8192];
  const int bid = blockIdx.x;

  const int axcd = bid & 7, aj = bid >> 3;
  const int abm = (aj >> 2) * 64;
  const int abn = (axcd*4 + (aj & 3)) * 64;
  const int b2 = bid - 128;
  const int bxcd = b2 & 7, bj = b2 >> 3;
  const int bbm = (bj >> 1) * 64;
  const int bbn = (bxcd*2 + (bj & 1)) * 64;

  int ep = 1;

  // ---- t = 0: h1 = tanh([x0|h0] @ [Wih|Whh]^T + brnn) (cached inputs) ----
  if (bid < 128){
    f32x4 acc[2][2] = {};
    gemm_core<AUX_CACHED>(Acat, 3072, Wcat, 3072, abm, abn, 48, acc, As, Bs);
    epi_h(acc, hb0, brnn, abm, abn);
  }
  step_barrier(bar, ep++, bid);

  const short* hc = hb0;
  short*       hn = hb1;
  for (int t = 1; t <= 255; ++t){
    if (bid < 128){
      f32x4 acc[2][2] = {};
      gemm_core<AUX_SYS>(hc, S_HIDDEN, Wcomb, S_HIDDEN, abm, abn, 32, acc, As, Bs);
      epi_h(acc, hn, cvec, abm, abn);
    } else {
      f32x4 acc[2][2] = {};
      gemm_core<AUX_SYS>(hc, S_HIDDEN, Wfcb, S_HIDDEN, bbm, bbn, 32, acc, As, Bs);
      epi_out(acc, out + (size_t)(t-1)*S_INPUT, bfc, bbm, bbn);
    }
    step_barrier(bar, ep++, bid);
    const short* tmp = hc; hc = hn; hn = (short*)tmp;
  }

  // ---- t = 256: out_255 = h_256 @ Wfc^T + b_fc (B-WGs) ----
  if (bid >= 128){
    f32x4 acc[2][2] = {};
    gemm_core<AUX_SYS>(hc, S_HIDDEN, Wfcb, S_HIDDEN, bbm, bbn, 32, acc, As, Bs);
    epi_out(acc, out + (size_t)255*S_INPUT, bfc, bbm, bbn);
  }
}

// ---------------------------------------------------------------------------
extern "C" void kernel_launch(void* const* d_in, const int* in_sizes, int n_in,
                              void* d_out, int out_size, void* d_ws, size_t ws_size,
                              hipStream_t stream)
{
  const float* x   = (const float*)d_in[0];   // (256,1,1024)
  const float* h0  = (const float*)d_in[1];   // (1,256,2048)
  const float* Wih = (const float*)d_in[2];   // (2048,1024)
  const float* Whh = (const float*)d_in[3];   // (2048,2048)
  const float* bih = (const float*)d_in[4];   // (2048)
  const float* bhh = (const float*)d_in[5];   // (2048)
  const float* Wfc = (const float*)d_in[6];   // (1024,2048)
  const float* bfc = (const float*)d_in[7];   // (1024)
  float* out = (float*)d_out;                 // (256,256,1024) f32

  char* ws = (char*)d_ws;
  size_t off = 0;
  auto alloc = [&](size_t bytes) -> void* {
    void* p = ws + off;
    off += (bytes + 255) & ~(size_t)255;
    return p;
  };
  short* Wcat = (short*)alloc((size_t)2048*3072*2);   // [W_ih | W_hh] bf16
  short* Acat = (short*)alloc((size_t)256*3072*2);    // [x0 | h0] bf16
  short* WfcT = (short*)alloc((size_t)2048*1024*2);   // W_fc^T bf16
  short* Wfcb = (short*)alloc((size_t)1024*2048*2);   // W_fc bf16
  short* Wcb  = (short*)alloc((size_t)2048*2048*2);   // Wcomb bf16
  short* hb0  = (short*)alloc((size_t)256*2048*2);
  short* hb1  = (short*)alloc((size_t)256*2048*2);
  float* brnn = (float*)alloc(2048*4);
  float* cvec = (float*)alloc(2048*4);
  unsigned* bar = (unsigned*)alloc(16384);
  (void)ws_size; (void)in_sizes; (void)n_in; (void)out_size;

  // Zero barrier flags/gen (captured in graph; re-runs stay deterministic)
  hipMemsetAsync(bar, 0, 16384, stream);

  // Prologue
  k_build_wcat<<<2048, 256, 0, stream>>>(Wih, Whh, Wcat);
  k_build_acat<<<256, 256, 0, stream>>>(x, h0, Acat);
  k_trans_wfc<<<dim3(32, 64), 256, 0, stream>>>(Wfc, Wfcb, WfcT);
  k_cvec<<<2048, 256, 0, stream>>>(Wih, bfc, bih, bhh, brnn, cvec);
  k_wcomb<<<1024, 256, 0, stream>>>(Wcat, WfcT, Whh, Wcb);

  // One persistent cooperative kernel for all 256 steps
  void* args[] = { (void*)&Acat, (void*)&Wcat, (void*)&brnn,
                   (void*)&Wcb,  (void*)&cvec,
                   (void*)&Wfcb, (void*)&bfc,
                   (void*)&hb0,  (void*)&hb1,
                   (void*)&out,  (void*)&bar };
  hipLaunchCooperativeKernel((const void*)k_persist, dim3(NWG_P), dim3(256),
                             args, 0, stream);
}